// Round 11
// baseline (894.353 us; speedup 1.0000x reference)
//
#include <hip/hip_runtime.h>
#include <math.h>

#define NN 50000
#define NE 800000
#define NB 64
#define TOT 850000  // NE + NN csr positions
#define LOG2E 1.4426950408889634f

// Lane-major position layout for conv1-space vectors (256 cols):
// original col c = head*64 + chan  ->  pos = chan*4 + (head ^ (chan&3))
__device__ __forceinline__ int permpos(int c) {
  return ((c & 63) << 2) | (((c >> 6) ^ c) & 3);
}

__device__ __forceinline__ unsigned short f2bf(float f) {
  unsigned int u = __float_as_uint(f);
  u += 0x7fffu + ((u >> 16) & 1u);   // RNE
  return (unsigned short)(u >> 16);
}
__device__ __forceinline__ float bf2f(unsigned short b) {
  return __uint_as_float(((unsigned int)b) << 16);
}

// ---------------- zero ----------------
__global__ void k_zero(int* __restrict__ p, int n) {
  int i = blockIdx.x * blockDim.x + threadIdx.x;
  if (i < n) p[i] = 0;
}

// ---------------- fused weight precompute ----------------
// br1e folds be@We1 (edge-bias) ; att1p/att2p pre-scaled by log2e.
__global__ void k_fuse(const float* __restrict__ Wn, const float* __restrict__ bn,
                       const float* __restrict__ We, const float* __restrict__ be,
                       const float* __restrict__ Wl1, const float* __restrict__ bl1,
                       const float* __restrict__ Wr1, const float* __restrict__ br1,
                       const float* __restrict__ We1, const float* __restrict__ We2,
                       const float* __restrict__ att1, const float* __restrict__ bias1,
                       const float* __restrict__ att2,
                       float* __restrict__ wl1e, float* __restrict__ bl1e,
                       float* __restrict__ wr1e, float* __restrict__ br1e,
                       float* __restrict__ wfe1, float* __restrict__ wfe2,
                       float* __restrict__ bfe2,
                       float* __restrict__ att1p, float* __restrict__ att2p,
                       float* __restrict__ bias1p) {
  int t = blockIdx.x * blockDim.x + threadIdx.x;
  if (t < 4096) {
    int i = t >> 8, j = t & 255; float s = 0.f;
    for (int k = 0; k < 64; k++) s += Wn[i * 64 + k] * Wl1[k * 256 + j];
    wl1e[i * 256 + permpos(j)] = s;
  } else if (t < 8192) {
    int u = t - 4096; int i = u >> 8, j = u & 255; float s = 0.f;
    for (int k = 0; k < 64; k++) s += Wn[i * 64 + k] * Wr1[k * 256 + j];
    wr1e[i * 256 + permpos(j)] = s;
  } else if (t < 10240) {
    int u = t - 8192; int i = u >> 8, j = u & 255; float s = 0.f;
    for (int k = 0; k < 64; k++) s += We[i * 64 + k] * We1[k * 256 + j];
    wfe1[i * 256 + permpos(j)] = s;
  } else if (t < 10752) {
    int u = t - 10240; int i = u >> 6, j = u & 63; float s = 0.f;
    for (int k = 0; k < 64; k++) s += We[i * 64 + k] * We2[k * 64 + j];
    wfe2[u] = s;
  } else if (t < 11008) {
    int j = t - 10752; float s = bl1[j];
    for (int k = 0; k < 64; k++) s += bn[k] * Wl1[k * 256 + j];
    bl1e[permpos(j)] = s;
  } else if (t < 11264) {
    int j = t - 11008; float s = br1[j];
    for (int k = 0; k < 64; k++) s += bn[k] * Wr1[k * 256 + j];
    for (int k = 0; k < 64; k++) s += be[k] * We1[k * 256 + j];  // fold edge bias
    br1e[permpos(j)] = s;
  } else if (t < 11328) {
    int j = t - 11264; float s = 0.f;
    for (int k = 0; k < 64; k++) s += be[k] * We2[k * 64 + j];
    bfe2[j] = s;
  } else if (t < 11584) {
    int j = t - 11328;
    att1p[permpos(j)] = att1[j] * LOG2E;
  } else if (t < 11648) {
    int j = t - 11584;
    att2p[j] = att2[j] * LOG2E;
  } else if (t < 11904) {
    int j = t - 11648;
    bias1p[permpos(j)] = bias1[j];
  }
}

// ---------------- degree only ----------------
__global__ void k_deg(const int* __restrict__ dstA, int* __restrict__ deg) {
  int e = blockIdx.x * blockDim.x + threadIdx.x;
  if (e < NE) atomicAdd(&deg[dstA[e]], 1);
}

// ---------------- 3-kernel scan of (deg+1) -> rowptr ----------------
__global__ __launch_bounds__(1024) void k_scan1(const int* __restrict__ deg,
                                                int* __restrict__ incl, int* __restrict__ partials) {
  __shared__ int sm[1024];
  int i = blockIdx.x * 1024 + threadIdx.x;
  int v = (i < NN) ? (deg[i] + 1) : 0;
  sm[threadIdx.x] = v;
  __syncthreads();
  for (int off = 1; off < 1024; off <<= 1) {
    int t = (threadIdx.x >= off) ? sm[threadIdx.x - off] : 0;
    __syncthreads();
    sm[threadIdx.x] += t;
    __syncthreads();
  }
  if (i < NN) incl[i] = sm[threadIdx.x];
  if (threadIdx.x == 1023) partials[blockIdx.x] = sm[1023];
}

__global__ void k_scan2(int* __restrict__ partials, int* __restrict__ rowptr, int nblk) {
  int t = threadIdx.x;
  int v = (t < nblk) ? partials[t] : 0;
  for (int off = 1; off < 64; off <<= 1) {
    int u = __shfl_up(v, off, 64);
    if (t >= off) v += u;
  }
  if (t < nblk) partials[t] = v;
  if (t == nblk - 1) rowptr[NN] = v;
}

__global__ void k_scan3(const int* __restrict__ deg, const int* __restrict__ incl,
                        const int* __restrict__ partials, int* __restrict__ rowptr) {
  int i = blockIdx.x * blockDim.x + threadIdx.x;
  if (i >= NN) return;
  int blk = i >> 10;
  int base = blk ? partials[blk - 1] : 0;
  rowptr[i] = base + incl[i] - (deg[i] + 1);
}

// ---------------- CSR fill: entry=(eid,src) + dstp[pos]; self-loop eid=NE+n at row end ----------------
__global__ void k_csr(const int* __restrict__ srcA, const int* __restrict__ dstA,
                      const int* __restrict__ rowptr, const int* __restrict__ deg,
                      int* __restrict__ cursor, int2* __restrict__ csr,
                      int* __restrict__ dstp) {
  int t = blockIdx.x * blockDim.x + threadIdx.x;
  if (t < NE) {
    int d = dstA[t];
    int pos = rowptr[d] + atomicAdd(&cursor[d], 1);
    csr[pos] = make_int2(t, srcA[t]);
    dstp[pos] = d;
  } else if (t < NE + NN) {
    int n = t - NE;
    int pos = rowptr[n] + deg[n];
    csr[pos] = make_int2(NE + n, n);
    dstp[pos] = n;
  }
}

// ---------------- per-node mean edge_attr (self-loop fill) ----------------
__global__ __launch_bounds__(256) void k_loop8(const int* __restrict__ rowptr,
                                               const int2* __restrict__ csr,
                                               const float* __restrict__ eattr,
                                               float* __restrict__ lattr) {
  int d = (blockIdx.x * blockDim.x + threadIdx.x) >> 6;
  int lane = threadIdx.x & 63;
  if (d >= NN) return;
  int beg = rowptr[d], endReal = rowptr[d + 1] - 1;
  int k = lane & 7, sub = lane >> 3;
  float s = 0.f;
  for (int i = beg + sub; i < endReal; i += 8) {
    int eid = csr[i].x;
    s += eattr[(size_t)eid * 8 + k];
  }
  s += __shfl_xor(s, 8, 64);
  s += __shfl_xor(s, 16, 64);
  s += __shfl_xor(s, 32, 64);
  float invdeg = 1.f / fmaxf((float)(endReal - beg), 1.f);
  if (lane < 8) lattr[(size_t)d * 8 + lane] = s * invdeg;
}

// ---------------- lin1: bf16 xl1 + f32 xrb1 (permpos, bfe folded via br1e) ----------------
__global__ __launch_bounds__(256) void k_lin1(const float* __restrict__ x,
                                              const float* __restrict__ wl, const float* __restrict__ bl,
                                              const float* __restrict__ wr, const float* __restrict__ br,
                                              unsigned short* __restrict__ xl, float* __restrict__ xr) {
  __shared__ float xs[4][16];
  int nb = blockIdx.x * 4;
  int t = threadIdx.x;
  if (t < 64) xs[t >> 4][t & 15] = x[nb * 16 + t];
  __syncthreads();
  int w = t >> 6, lane = t & 63, l4 = lane << 2;
  float4 accl = *(const float4*)(bl + l4);
  float4 accr = *(const float4*)(br + l4);
  const float* xrow = xs[w];
#pragma unroll
  for (int k = 0; k < 16; k++) {
    float xv = xrow[k];
    float4 wl4 = *(const float4*)(wl + k * 256 + l4);
    float4 wr4 = *(const float4*)(wr + k * 256 + l4);
    accl.x += xv * wl4.x; accl.y += xv * wl4.y; accl.z += xv * wl4.z; accl.w += xv * wl4.w;
    accr.x += xv * wr4.x; accr.y += xv * wr4.y; accr.z += xv * wr4.z; accr.w += xv * wr4.w;
  }
  int node = nb + w;
  ushort4 us;
  us.x = f2bf(accl.x); us.y = f2bf(accl.y); us.z = f2bf(accl.z); us.w = f2bf(accl.w);
  *(ushort4*)(xl + (size_t)node * 256 + l4) = us;
  *(float4*)(xr + (size_t)node * 256 + l4) = accr;
}

// scalar edge-attr pointer (eid wave-uniform)
__device__ __forceinline__ const float* ek_ptr(const float* __restrict__ eattr,
                                               const float* __restrict__ lattr, int eid) {
  return (eid < NE) ? (eattr + (size_t)eid * 8) : (lattr + (size_t)(eid - NE) * 8);
}

// j-space logit reduction (conv1): 7 shuffles.
__device__ __forceinline__ float jreduce(float part[4]) {
  part[0] += __shfl_xor(part[1], 1, 64);
  part[2] += __shfl_xor(part[3], 1, 64);
  float v = part[0] + __shfl_xor(part[2], 2, 64);
  v += __shfl_xor(v, 4, 64);
  v += __shfl_xor(v, 8, 64);
  v += __shfl_xor(v, 16, 64);
  v += __shfl_xor(v, 32, 64);
  return v;
}

// ---------------- elogit1: fully-parallel per-position 4-head logits (log2 domain) ----------------
__global__ __launch_bounds__(256) void k_elogit1(
    const float* __restrict__ eattr, const float* __restrict__ lattr,
    const int2* __restrict__ csr, const int* __restrict__ dstp,
    const unsigned short* __restrict__ xl, const float* __restrict__ xrb,
    const float* __restrict__ att1p, const float* __restrict__ wfe1,
    float* __restrict__ logit1) {
  int wid = (blockIdx.x * blockDim.x + threadIdx.x) >> 6;
  int lane = threadIdx.x & 63;
  int p0 = wid * 4;
  int l4 = lane << 2;
  float4 at4 = *(const float4*)(att1p + l4);
  float4 wf[8];
#pragma unroll
  for (int k = 0; k < 8; k++) wf[k] = *(const float4*)(wfe1 + k * 256 + l4);
  float v[4];
#pragma unroll
  for (int i = 0; i < 4; i++) {
    int p = p0 + i;
    int2 e = csr[p];
    int eid = __builtin_amdgcn_readfirstlane(e.x);
    int s   = __builtin_amdgcn_readfirstlane(e.y);
    int dd  = __builtin_amdgcn_readfirstlane(dstp[p]);
    const float* ekp = ek_ptr(eattr, lattr, eid);
    float4 xb = *(const float4*)(xrb + (size_t)dd * 256 + l4);
    ushort4 u = *(const ushort4*)(xl + (size_t)s * 256 + l4);
    float m0 = xb.x + bf2f(u.x);
    float m1 = xb.y + bf2f(u.y);
    float m2 = xb.z + bf2f(u.z);
    float m3 = xb.w + bf2f(u.w);
#pragma unroll
    for (int k = 0; k < 8; k++) {
      float ekv = ekp[k];
      m0 += ekv * wf[k].x; m1 += ekv * wf[k].y;
      m2 += ekv * wf[k].z; m3 += ekv * wf[k].w;
    }
    m0 = (m0 > 0.f) ? m0 : 0.2f * m0;
    m1 = (m1 > 0.f) ? m1 : 0.2f * m1;
    m2 = (m2 > 0.f) ? m2 : 0.2f * m2;
    m3 = (m3 > 0.f) ? m3 : 0.2f * m3;
    float part[4] = {at4.x * m0, at4.y * m1, at4.z * m2, at4.w * m3};
    v[i] = jreduce(part);  // head (lane&3) logit, every lane
  }
  int key = (lane >> 2) & 3;
  float a = (key & 1) ? v[1] : v[0];
  float b = (key & 1) ? v[3] : v[2];
  float out = (key & 2) ? b : a;
  if (lane < 16) logit1[(size_t)p0 * 4 + lane] = out;
}

// ---------------- conv1-lite: softmax-gather with precomputed logits ----------------
__global__ __launch_bounds__(256) void k_conv1l(
    const int* __restrict__ rowptr, const int2* __restrict__ csr,
    const float* __restrict__ logit1,
    const unsigned short* __restrict__ xl,
    const float* __restrict__ bias1p,
    float* __restrict__ out1) {
  int d = __builtin_amdgcn_readfirstlane((blockIdx.x * blockDim.x + threadIdx.x) >> 6);
  int lane = threadIdx.x & 63;
  if (d >= NN) return;
  int l4 = lane << 2;
  int k = lane & 3;
  float acc0 = 0.f, acc1 = 0.f, acc2 = 0.f, acc3 = 0.f;
  float mrun = -INFINITY, lrun = 0.f;
  int beg = rowptr[d], end = rowptr[d + 1];

  auto ld4 = [&](int s) -> float4 {
    ushort4 u = *(const ushort4*)(xl + (size_t)s * 256 + l4);
    float4 f; f.x = bf2f(u.x); f.y = bf2f(u.y); f.z = bf2f(u.z); f.w = bf2f(u.w);
    return f;
  };
  auto sel = [&](const float4& lg) -> float {
    float a = (k & 1) ? lg.y : lg.x;
    float b = (k & 1) ? lg.w : lg.z;
    return (k & 2) ? b : a;
  };

  int idx = beg;
  for (; idx + 4 <= end; idx += 4) {
    int2 e0 = csr[idx], e1 = csr[idx + 1], e2 = csr[idx + 2], e3 = csr[idx + 3];
    int s0 = __builtin_amdgcn_readfirstlane(e0.y);
    int s1 = __builtin_amdgcn_readfirstlane(e1.y);
    int s2 = __builtin_amdgcn_readfirstlane(e2.y);
    int s3 = __builtin_amdgcn_readfirstlane(e3.y);
    const float4* lgp = (const float4*)(logit1 + (size_t)idx * 4);
    float4 lg0 = lgp[0], lg1 = lgp[1], lg2 = lgp[2], lg3 = lgp[3];
    float v0 = sel(lg0), v1 = sel(lg1), v2 = sel(lg2), v3 = sel(lg3);
    float4 x0 = ld4(s0), x1 = ld4(s1), x2 = ld4(s2), x3 = ld4(s3);
    float gmax = fmaxf(fmaxf(v0, v1), fmaxf(v2, v3));
    if (__ballot(gmax > mrun)) {
      float nm = fmaxf(mrun, gmax);
      float sc = exp2f(mrun - nm);
      mrun = nm; lrun *= sc;
      float sc1 = __shfl_xor(sc, 1, 64);
      float sc2 = __shfl_xor(sc, 2, 64);
      float sc3 = __shfl_xor(sc1, 2, 64);
      acc0 *= sc; acc1 *= sc1; acc2 *= sc2; acc3 *= sc3;
    }
    float q0 = exp2f(v0 - mrun), q1 = exp2f(v1 - mrun);
    float q2 = exp2f(v2 - mrun), q3 = exp2f(v3 - mrun);
    lrun += (q0 + q1) + (q2 + q3);
    {
      float a1 = __shfl_xor(q0, 1, 64), a2 = __shfl_xor(q0, 2, 64), a3 = __shfl_xor(a1, 2, 64);
      acc0 += q0 * x0.x; acc1 += a1 * x0.y; acc2 += a2 * x0.z; acc3 += a3 * x0.w;
    }
    {
      float a1 = __shfl_xor(q1, 1, 64), a2 = __shfl_xor(q1, 2, 64), a3 = __shfl_xor(a1, 2, 64);
      acc0 += q1 * x1.x; acc1 += a1 * x1.y; acc2 += a2 * x1.z; acc3 += a3 * x1.w;
    }
    {
      float a1 = __shfl_xor(q2, 1, 64), a2 = __shfl_xor(q2, 2, 64), a3 = __shfl_xor(a1, 2, 64);
      acc0 += q2 * x2.x; acc1 += a1 * x2.y; acc2 += a2 * x2.z; acc3 += a3 * x2.w;
    }
    {
      float a1 = __shfl_xor(q3, 1, 64), a2 = __shfl_xor(q3, 2, 64), a3 = __shfl_xor(a1, 2, 64);
      acc0 += q3 * x3.x; acc1 += a1 * x3.y; acc2 += a2 * x3.z; acc3 += a3 * x3.w;
    }
  }
  for (; idx < end; ++idx) {
    int2 e0 = csr[idx];
    int s0 = __builtin_amdgcn_readfirstlane(e0.y);
    float4 lg0 = *(const float4*)(logit1 + (size_t)idx * 4);
    float v0 = sel(lg0);
    float4 x0 = ld4(s0);
    if (__ballot(v0 > mrun)) {
      float nm = fmaxf(mrun, v0);
      float sc = exp2f(mrun - nm);
      mrun = nm; lrun *= sc;
      float sc1 = __shfl_xor(sc, 1, 64);
      float sc2 = __shfl_xor(sc, 2, 64);
      float sc3 = __shfl_xor(sc1, 2, 64);
      acc0 *= sc; acc1 *= sc1; acc2 *= sc2; acc3 *= sc3;
    }
    float q0 = exp2f(v0 - mrun);
    lrun += q0;
    float a1 = __shfl_xor(q0, 1, 64), a2 = __shfl_xor(q0, 2, 64), a3 = __shfl_xor(a1, 2, 64);
    acc0 += q0 * x0.x; acc1 += a1 * x0.y; acc2 += a2 * x0.z; acc3 += a3 * x0.w;
  }

  float lr0 = lrun;
  float lr1 = __shfl_xor(lr0, 1, 64);
  float lr2 = __shfl_xor(lr0, 2, 64);
  float lr3 = __shfl_xor(lr1, 2, 64);
  float4 bi4 = *(const float4*)(bias1p + l4);
  float4 o;
  o.x = acc0 / (lr0 + 1e-16f) + bi4.x;
  o.y = acc1 / (lr1 + 1e-16f) + bi4.y;
  o.z = acc2 / (lr2 + 1e-16f) + bi4.z;
  o.w = acc3 / (lr3 + 1e-16f) + bi4.w;
  o.x = (o.x > 0.f) ? o.x : (__expf(o.x) - 1.f);
  o.y = (o.y > 0.f) ? o.y : (__expf(o.y) - 1.f);
  o.z = (o.z > 0.f) ? o.z : (__expf(o.z) - 1.f);
  o.w = (o.w > 0.f) ? o.w : (__expf(o.w) - 1.f);
  *(float4*)(out1 + (size_t)d * 256 + l4) = o;
}

// ---------------- lin2: permpos out1 -> bf16 xl2 + f32 xrb2 (bfe2 folded) ----------------
__global__ __launch_bounds__(256) void k_lin2(const float* __restrict__ in,
                                              const float* __restrict__ wl, const float* __restrict__ bl,
                                              const float* __restrict__ wr, const float* __restrict__ br,
                                              const float* __restrict__ bfe2,
                                              unsigned short* __restrict__ xl, float* __restrict__ xr) {
  int col = threadIdx.x & 63;
  int grp = threadIdx.x >> 6;
  int node0 = blockIdx.x * 32 + grp * 8;
  float sl[8], sr[8];
  float blv = bl[col], brv = br[col] + bfe2[col];
#pragma unroll
  for (int u = 0; u < 8; u++) { sl[u] = blv; sr[u] = brv; }
  const float4* r[8];
#pragma unroll
  for (int u = 0; u < 8; u++) r[u] = (const float4*)(in + (size_t)(node0 + u) * 256);
#pragma unroll 2
  for (int g4 = 0; g4 < 64; g4++) {
    int b = g4 & 3;
    int i0 = ((0 ^ b) << 6) + g4;
    int i1 = ((1 ^ b) << 6) + g4;
    int i2 = ((2 ^ b) << 6) + g4;
    int i3 = ((3 ^ b) << 6) + g4;
    float wl0 = wl[i0 * 64 + col], wl1v = wl[i1 * 64 + col];
    float wl2v = wl[i2 * 64 + col], wl3v = wl[i3 * 64 + col];
    float wr0 = wr[i0 * 64 + col], wr1v = wr[i1 * 64 + col];
    float wr2v = wr[i2 * 64 + col], wr3v = wr[i3 * 64 + col];
#pragma unroll
    for (int u = 0; u < 8; u++) {
      float4 v = r[u][g4];
      sl[u] += v.x * wl0 + v.y * wl1v + v.z * wl2v + v.w * wl3v;
      sr[u] += v.x * wr0 + v.y * wr1v + v.z * wr2v + v.w * wr3v;
    }
  }
#pragma unroll
  for (int u = 0; u < 8; u++) {
    int node = node0 + u;
    if (node < NN) {
      xl[(size_t)node * 64 + col] = f2bf(sl[u]);
      xr[(size_t)node * 64 + col] = sr[u];
    }
  }
}

// ---------------- elogit2: fully-parallel per-position 1-head logit (log2 domain) ----------------
__global__ __launch_bounds__(256) void k_elogit2(
    const float* __restrict__ eattr, const float* __restrict__ lattr,
    const int2* __restrict__ csr, const int* __restrict__ dstp,
    const unsigned short* __restrict__ xl, const float* __restrict__ xrb,
    const float* __restrict__ att2p, const float* __restrict__ wfe2,
    float* __restrict__ logit2) {
  int wid = (blockIdx.x * blockDim.x + threadIdx.x) >> 6;
  int lane = threadIdx.x & 63;
  int p0 = wid * 4;
  float att_l = att2p[lane];
  float wfe_l[8];
#pragma unroll
  for (int k = 0; k < 8; k++) wfe_l[k] = wfe2[k * 64 + lane];
  float v[4];
#pragma unroll
  for (int i = 0; i < 4; i++) {
    int p = p0 + i;
    int2 e = csr[p];
    int eid = __builtin_amdgcn_readfirstlane(e.x);
    int s   = __builtin_amdgcn_readfirstlane(e.y);
    int dd  = __builtin_amdgcn_readfirstlane(dstp[p]);
    const float* ekp = ek_ptr(eattr, lattr, eid);
    float m = xrb[(size_t)dd * 64 + lane] + bf2f(xl[(size_t)s * 64 + lane]);
#pragma unroll
    for (int k = 0; k < 8; k++) m += ekp[k] * wfe_l[k];
    m = (m > 0.f) ? m : 0.2f * m;
    float t = att_l * m;
    t += __shfl_xor(t, 1, 64);
    t += __shfl_xor(t, 2, 64);
    t += __shfl_xor(t, 4, 64);
    t += __shfl_xor(t, 8, 64);
    t += __shfl_xor(t, 16, 64);
    t += __shfl_xor(t, 32, 64);
    v[i] = t;  // uniform
  }
  int key = lane & 3;
  float a = (key & 1) ? v[1] : v[0];
  float b = (key & 1) ? v[3] : v[2];
  float out = (key & 2) ? b : a;
  if (lane < 4) logit2[p0 + lane] = out;
}

// ---------------- conv2-lite ----------------
__global__ __launch_bounds__(256) void k_conv2l(
    const int* __restrict__ rowptr, const int2* __restrict__ csr,
    const float* __restrict__ logit2,
    const unsigned short* __restrict__ xl,
    const float* __restrict__ bias2,
    float* __restrict__ out2) {
  int d = __builtin_amdgcn_readfirstlane((blockIdx.x * blockDim.x + threadIdx.x) >> 6);
  int lane = threadIdx.x & 63;
  if (d >= NN) return;
  float acc = 0.f, mrun = -INFINITY, lrun = 0.f;
  int beg = rowptr[d], end = rowptr[d + 1];

  int idx = beg;
  for (; idx + 4 <= end; idx += 4) {
    int2 e0 = csr[idx], e1 = csr[idx + 1], e2 = csr[idx + 2], e3 = csr[idx + 3];
    int s0 = __builtin_amdgcn_readfirstlane(e0.y);
    int s1 = __builtin_amdgcn_readfirstlane(e1.y);
    int s2 = __builtin_amdgcn_readfirstlane(e2.y);
    int s3 = __builtin_amdgcn_readfirstlane(e3.y);
    float l0 = logit2[idx], l1 = logit2[idx + 1], l2 = logit2[idx + 2], l3 = logit2[idx + 3];
    float x0 = bf2f(xl[(size_t)s0 * 64 + lane]);
    float x1 = bf2f(xl[(size_t)s1 * 64 + lane]);
    float x2 = bf2f(xl[(size_t)s2 * 64 + lane]);
    float x3 = bf2f(xl[(size_t)s3 * 64 + lane]);
    float g = fmaxf(fmaxf(l0, l1), fmaxf(l2, l3));
    if (g > mrun) {  // uniform branch
      float sc = exp2f(mrun - g);
      mrun = g; lrun *= sc; acc *= sc;
    }
    float q0 = exp2f(l0 - mrun), q1 = exp2f(l1 - mrun);
    float q2 = exp2f(l2 - mrun), q3 = exp2f(l3 - mrun);
    lrun += (q0 + q1) + (q2 + q3);
    acc += q0 * x0 + q1 * x1 + q2 * x2 + q3 * x3;
  }
  for (; idx < end; ++idx) {
    int2 e0 = csr[idx];
    int s0 = __builtin_amdgcn_readfirstlane(e0.y);
    float l0 = logit2[idx];
    float x0 = bf2f(xl[(size_t)s0 * 64 + lane]);
    if (l0 > mrun) {
      float sc = exp2f(mrun - l0);
      mrun = l0; lrun *= sc; acc *= sc;
    }
    float q = exp2f(l0 - mrun);
    lrun += q;
    acc += q * x0;
  }
  out2[(size_t)d * 64 + lane] = acc / (lrun + 1e-16f) + bias2[lane];
}

// ---------------- global mean pool ----------------
__device__ __forceinline__ int lowerb(const int* a, int n, int v) {
  int lo = 0, hi = n;
  while (lo < hi) {
    int mid = (lo + hi) >> 1;
    if (a[mid] < v) lo = mid + 1; else hi = mid;
  }
  return lo;
}

__global__ __launch_bounds__(256) void k_pool(const int* __restrict__ batch,
                                              const float* __restrict__ out2,
                                              float* __restrict__ pooled) {
  int b = blockIdx.x;
  int start = lowerb(batch, NN, b);
  int end = lowerb(batch, NN, b + 1);
  int c = threadIdx.x & 63, sub = threadIdx.x >> 6;
  float s = 0.f;
  for (int i = start + sub; i < end; i += 4) s += out2[(size_t)i * 64 + c];
  __shared__ float sm[256];
  sm[threadIdx.x] = s;
  __syncthreads();
  if (sub == 0) {
    float tot = sm[c] + sm[64 + c] + sm[128 + c] + sm[192 + c];
    float cnt = fmaxf((float)(end - start), 1.f);
    pooled[b * 64 + c] = tot / cnt;
  }
}

// ---------------- decoder ----------------
__global__ __launch_bounds__(1024) void k_dec(const float* __restrict__ pooled,
                                              const float* __restrict__ Wd1, const float* __restrict__ bd1,
                                              const float* __restrict__ Wd2, const float* __restrict__ bd2,
                                              float* __restrict__ out) {
  __shared__ float hid[64 * 64];
  int t = threadIdx.x;
  for (int i = t; i < 4096; i += 1024) {
    int b = i >> 6, j = i & 63;
    float s = bd1[j];
#pragma unroll 8
    for (int k = 0; k < 64; k++) s += pooled[b * 64 + k] * Wd1[k * 64 + j];
    hid[i] = fmaxf(s, 0.f);
  }
  __syncthreads();
  if (t < 128) {
    int b = t >> 1, o = t & 1;
    float s = bd2[o];
#pragma unroll 8
    for (int k = 0; k < 64; k++) s += hid[b * 64 + k] * Wd2[k * 2 + o];
    out[t] = 1.f / (1.f + __expf(-s));
  }
}

extern "C" void kernel_launch(void* const* d_in, const int* in_sizes, int n_in,
                              void* d_out, int out_size, void* d_ws, size_t ws_size,
                              hipStream_t stream) {
  const float* x     = (const float*)d_in[0];
  const int*   eidx  = (const int*)d_in[1];
  const float* eattr = (const float*)d_in[2];
  const int*   batch = (const int*)d_in[3];
  const float* Wn    = (const float*)d_in[4];
  const float* bn    = (const float*)d_in[5];
  const float* We    = (const float*)d_in[6];
  const float* be    = (const float*)d_in[7];
  const float* Wl1   = (const float*)d_in[8];
  const float* bl1   = (const float*)d_in[9];
  const float* Wr1   = (const float*)d_in[10];
  const float* br1   = (const float*)d_in[11];
  const float* We1   = (const float*)d_in[12];
  const float* att1  = (const float*)d_in[13];
  const float* bias1 = (const float*)d_in[14];
  const float* Wl2   = (const float*)d_in[15];
  const float* bl2   = (const float*)d_in[16];
  const float* Wr2   = (const float*)d_in[17];
  const float* br2   = (const float*)d_in[18];
  const float* We2   = (const float*)d_in[19];
  const float* att2  = (const float*)d_in[20];
  const float* bias2 = (const float*)d_in[21];
  const float* Wd1   = (const float*)d_in[22];
  const float* bd1   = (const float*)d_in[23];
  const float* Wd2   = (const float*)d_in[24];
  const float* bd2   = (const float*)d_in[25];

  const int* srcA = eidx;
  const int* dstA = eidx + NE;

  char* ws = (char*)d_ws;
  size_t off = 0;
  auto alloc = [&](size_t bytes) -> char* {
    char* p = ws + off;
    off += (bytes + 255) & ~(size_t)255;
    return p;
  };

  // zero region (deg, cursor) must stay first & contiguous
  int*   deg    = (int*)alloc(NN * 4);
  int*   cursor = (int*)alloc(NN * 4);
  size_t zero_bytes = off;
  int*   rowptr   = (int*)alloc((NN + 1) * 4);
  int*   incl     = (int*)alloc(NN * 4);
  int*   partials = (int*)alloc(64 * 4);
  int2*  csr      = (int2*)alloc((size_t)(TOT + 1) * 8);
  int*   dstp     = (int*)alloc((size_t)TOT * 4);
  float* lattr = (float*)alloc((size_t)NN * 8 * 4);
  float* wl1e  = (float*)alloc(4096 * 4);
  float* wr1e  = (float*)alloc(4096 * 4);
  float* wfe1  = (float*)alloc(2048 * 4);
  float* wfe2  = (float*)alloc(512 * 4);
  float* bl1e  = (float*)alloc(256 * 4);
  float* br1e  = (float*)alloc(256 * 4);
  float* bfe2  = (float*)alloc(64 * 4);
  float* att1p = (float*)alloc(256 * 4);
  float* att2p = (float*)alloc(64 * 4);
  float* bias1p= (float*)alloc(256 * 4);
  unsigned short* xl1 = (unsigned short*)alloc((size_t)NN * 256 * 2);
  float* xrb1  = (float*)alloc((size_t)NN * 256 * 4);
  float* out1  = (float*)alloc((size_t)NN * 256 * 4);
  unsigned short* xl2 = (unsigned short*)alloc((size_t)NN * 64 * 2);
  float* xrb2  = (float*)alloc((size_t)NN * 64 * 4);
  float* out2  = (float*)alloc((size_t)NN * 64 * 4);
  float* logit1 = (float*)alloc((size_t)TOT * 4 * 4);
  float* logit2 = (float*)alloc((size_t)TOT * 4);
  float* pooled = (float*)alloc((size_t)NB * 64 * 4);

  int zn = (int)(zero_bytes / 4);
  int nscan = (NN + 1023) / 1024;  // 49
  int nelog = TOT / 16;            // 53125 blocks, exact
  k_zero<<<(zn + 255) / 256, 256, 0, stream>>>((int*)d_ws, zn);
  k_fuse<<<(11904 + 255) / 256, 256, 0, stream>>>(Wn, bn, We, be, Wl1, bl1, Wr1, br1, We1, We2,
                                                  att1, bias1, att2,
                                                  wl1e, bl1e, wr1e, br1e, wfe1, wfe2, bfe2,
                                                  att1p, att2p, bias1p);
  k_deg<<<(NE + 255) / 256, 256, 0, stream>>>(dstA, deg);
  k_scan1<<<nscan, 1024, 0, stream>>>(deg, incl, partials);
  k_scan2<<<1, 64, 0, stream>>>(partials, rowptr, nscan);
  k_scan3<<<(NN + 255) / 256, 256, 0, stream>>>(deg, incl, partials, rowptr);
  k_csr<<<(NE + NN + 255) / 256, 256, 0, stream>>>(srcA, dstA, rowptr, deg, cursor, csr, dstp);
  k_loop8<<<(NN + 3) / 4, 256, 0, stream>>>(rowptr, csr, eattr, lattr);
  k_lin1<<<NN / 4, 256, 0, stream>>>(x, wl1e, bl1e, wr1e, br1e, xl1, xrb1);
  k_elogit1<<<nelog, 256, 0, stream>>>(eattr, lattr, csr, dstp, xl1, xrb1, att1p, wfe1, logit1);
  k_conv1l<<<(NN + 3) / 4, 256, 0, stream>>>(rowptr, csr, logit1, xl1, bias1p, out1);
  k_lin2<<<(NN + 31) / 32, 256, 0, stream>>>(out1, Wl2, bl2, Wr2, br2, bfe2, xl2, xrb2);
  k_elogit2<<<nelog, 256, 0, stream>>>(eattr, lattr, csr, dstp, xl2, xrb2, att2p, wfe2, logit2);
  k_conv2l<<<(NN + 3) / 4, 256, 0, stream>>>(rowptr, csr, logit2, xl2, bias2, out2);
  k_pool<<<NB, 256, 0, stream>>>(batch, out2, pooled);
  k_dec<<<1, 1024, 0, stream>>>(pooled, Wd1, bd1, Wd2, bd2, (float*)d_out);
}

// Round 12
// 734.380 us; speedup vs baseline: 1.2178x; 1.2178x over previous
//
#include <hip/hip_runtime.h>
#include <math.h>

#define NN 50000
#define NE 800000
#define NB 64
#define LOG2E 1.4426950408889634f

typedef _Float16 h2 __attribute__((ext_vector_type(2)));

#if __has_builtin(__builtin_amdgcn_fdot2)
__device__ __forceinline__ float FDOT2(h2 a, h2 b, float c) {
  return __builtin_amdgcn_fdot2(a, b, c, false);
}
#else
__device__ __forceinline__ float FDOT2(h2 a, h2 b, float c) {
  return c + (float)a.x * (float)b.x + (float)a.y * (float)b.y;
}
#endif

// Lane-major position layout for conv1-space vectors (256 cols):
// original col c = head*64 + chan  ->  pos = chan*4 + (head ^ (chan&3))
__device__ __forceinline__ int permpos(int c) {
  return ((c & 63) << 2) | (((c >> 6) ^ c) & 3);
}
// inverse: pos p -> orig col
__device__ __forceinline__ int invpos(int p) {
  return ((((p & 3) ^ ((p >> 2) & 3)) & 3) << 6) | (p >> 2);
}

__device__ __forceinline__ unsigned short f2bf(float f) {
  unsigned int u = __float_as_uint(f);
  u += 0x7fffu + ((u >> 16) & 1u);   // RNE
  return (unsigned short)(u >> 16);
}
__device__ __forceinline__ float bf2f(unsigned short b) {
  return __uint_as_float(((unsigned int)b) << 16);
}

// ---------------- zero ----------------
__global__ void k_zero(int* __restrict__ p, int n) {
  int i = blockIdx.x * blockDim.x + threadIdx.x;
  if (i < n) p[i] = 0;
}

// ---------------- fused weight precompute ----------------
// br1e folds be@We1; att pre-scaled by log2e; edge weights stored as half2 pairs.
__global__ void k_fuse(const float* __restrict__ Wn, const float* __restrict__ bn,
                       const float* __restrict__ We, const float* __restrict__ be,
                       const float* __restrict__ Wl1, const float* __restrict__ bl1,
                       const float* __restrict__ Wr1, const float* __restrict__ br1,
                       const float* __restrict__ We1, const float* __restrict__ We2,
                       const float* __restrict__ att1, const float* __restrict__ bias1,
                       const float* __restrict__ att2,
                       float* __restrict__ wl1e, float* __restrict__ bl1e,
                       float* __restrict__ wr1e, float* __restrict__ br1e,
                       h2* __restrict__ wfh1, h2* __restrict__ wfh2,
                       float* __restrict__ bfe2,
                       float* __restrict__ att1p, float* __restrict__ att2p,
                       float* __restrict__ bias1p) {
  int t = blockIdx.x * blockDim.x + threadIdx.x;
  if (t < 4096) {
    int i = t >> 8, j = t & 255; float s = 0.f;
    for (int k = 0; k < 64; k++) s += Wn[i * 64 + k] * Wl1[k * 256 + j];
    wl1e[i * 256 + permpos(j)] = s;
  } else if (t < 8192) {
    int u = t - 4096; int i = u >> 8, j = u & 255; float s = 0.f;
    for (int k = 0; k < 64; k++) s += Wn[i * 64 + k] * Wr1[k * 256 + j];
    wr1e[i * 256 + permpos(j)] = s;
  } else if (t < 9216) {
    int u = t - 8192;              // wfh1: [k2][pos], 4*256
    int k2 = u >> 8, p = u & 255;
    int c = invpos(p);
    float lo = 0.f, hi = 0.f;
    for (int k = 0; k < 64; k++) {
      lo += We[(2 * k2) * 64 + k] * We1[k * 256 + c];
      hi += We[(2 * k2 + 1) * 64 + k] * We1[k * 256 + c];
    }
    h2 v; v.x = (_Float16)lo; v.y = (_Float16)hi;
    wfh1[u] = v;
  } else if (t < 9472) {
    int u = t - 9216;              // wfh2: [k2][chan], 4*64
    int k2 = u >> 6, c = u & 63;
    float lo = 0.f, hi = 0.f;
    for (int k = 0; k < 64; k++) {
      lo += We[(2 * k2) * 64 + k] * We2[k * 64 + c];
      hi += We[(2 * k2 + 1) * 64 + k] * We2[k * 64 + c];
    }
    h2 v; v.x = (_Float16)lo; v.y = (_Float16)hi;
    wfh2[u] = v;
  } else if (t < 9728) {
    int j = t - 9472; float s = bl1[j];
    for (int k = 0; k < 64; k++) s += bn[k] * Wl1[k * 256 + j];
    bl1e[permpos(j)] = s;
  } else if (t < 9984) {
    int j = t - 9728; float s = br1[j];
    for (int k = 0; k < 64; k++) s += bn[k] * Wr1[k * 256 + j];
    for (int k = 0; k < 64; k++) s += be[k] * We1[k * 256 + j];  // fold edge bias
    br1e[permpos(j)] = s;
  } else if (t < 10048) {
    int j = t - 9984; float s = 0.f;
    for (int k = 0; k < 64; k++) s += be[k] * We2[k * 64 + j];
    bfe2[j] = s;
  } else if (t < 10304) {
    int j = t - 10048;
    att1p[permpos(j)] = att1[j] * LOG2E;
  } else if (t < 10368) {
    int j = t - 10304;
    att2p[j] = att2[j] * LOG2E;
  } else if (t < 10624) {
    int j = t - 10368;
    bias1p[permpos(j)] = bias1[j];
  }
}

// ---------------- eattr -> half ----------------
__global__ void k_toh(const float* __restrict__ eattr, h2* __restrict__ ehalf) {
  int e = blockIdx.x * blockDim.x + threadIdx.x;
  if (e >= NE) return;
  float4 a = *(const float4*)(eattr + (size_t)e * 8);
  float4 b = *(const float4*)(eattr + (size_t)e * 8 + 4);
  h2 o[4];
  o[0].x = (_Float16)a.x; o[0].y = (_Float16)a.y;
  o[1].x = (_Float16)a.z; o[1].y = (_Float16)a.w;
  o[2].x = (_Float16)b.x; o[2].y = (_Float16)b.y;
  o[3].x = (_Float16)b.z; o[3].y = (_Float16)b.w;
  *(uint4*)(ehalf + (size_t)e * 4) = *(uint4*)o;
}

// ---------------- degree only ----------------
__global__ void k_deg(const int* __restrict__ dstA, int* __restrict__ deg) {
  int e = blockIdx.x * blockDim.x + threadIdx.x;
  if (e < NE) atomicAdd(&deg[dstA[e]], 1);
}

// ---------------- 3-kernel scan of (deg+1) -> rowptr ----------------
__global__ __launch_bounds__(1024) void k_scan1(const int* __restrict__ deg,
                                                int* __restrict__ incl, int* __restrict__ partials) {
  __shared__ int sm[1024];
  int i = blockIdx.x * 1024 + threadIdx.x;
  int v = (i < NN) ? (deg[i] + 1) : 0;
  sm[threadIdx.x] = v;
  __syncthreads();
  for (int off = 1; off < 1024; off <<= 1) {
    int t = (threadIdx.x >= off) ? sm[threadIdx.x - off] : 0;
    __syncthreads();
    sm[threadIdx.x] += t;
    __syncthreads();
  }
  if (i < NN) incl[i] = sm[threadIdx.x];
  if (threadIdx.x == 1023) partials[blockIdx.x] = sm[1023];
}

__global__ void k_scan2(int* __restrict__ partials, int* __restrict__ rowptr, int nblk) {
  int t = threadIdx.x;
  int v = (t < nblk) ? partials[t] : 0;
  for (int off = 1; off < 64; off <<= 1) {
    int u = __shfl_up(v, off, 64);
    if (t >= off) v += u;
  }
  if (t < nblk) partials[t] = v;
  if (t == nblk - 1) rowptr[NN] = v;
}

__global__ void k_scan3(const int* __restrict__ deg, const int* __restrict__ incl,
                        const int* __restrict__ partials, int* __restrict__ rowptr) {
  int i = blockIdx.x * blockDim.x + threadIdx.x;
  if (i >= NN) return;
  int blk = i >> 10;
  int base = blk ? partials[blk - 1] : 0;
  rowptr[i] = base + incl[i] - (deg[i] + 1);
}

// ---------------- CSR fill: entry=(eid,src); self-loop eid=NE+n at row end ----------------
__global__ void k_csr(const int* __restrict__ srcA, const int* __restrict__ dstA,
                      const int* __restrict__ rowptr, const int* __restrict__ deg,
                      int* __restrict__ cursor, int2* __restrict__ csr) {
  int t = blockIdx.x * blockDim.x + threadIdx.x;
  if (t < NE) {
    int d = dstA[t];
    int pos = rowptr[d] + atomicAdd(&cursor[d], 1);
    csr[pos] = make_int2(t, srcA[t]);
  } else if (t < NE + NN) {
    int n = t - NE;
    csr[rowptr[n] + deg[n]] = make_int2(NE + n, n);
  }
}

// ---------------- per-node mean edge_attr (self-loop fill, half output) ----------------
__global__ __launch_bounds__(256) void k_loop8(const int* __restrict__ rowptr,
                                               const int2* __restrict__ csr,
                                               const float* __restrict__ eattr,
                                               h2* __restrict__ lattrh) {
  int d = (blockIdx.x * blockDim.x + threadIdx.x) >> 6;
  int lane = threadIdx.x & 63;
  if (d >= NN) return;
  int beg = rowptr[d], endReal = rowptr[d + 1] - 1;
  int k = lane & 7, sub = lane >> 3;
  float s = 0.f;
  for (int i = beg + sub; i < endReal; i += 8) {
    int eid = csr[i].x;
    s += eattr[(size_t)eid * 8 + k];
  }
  s += __shfl_xor(s, 8, 64);
  s += __shfl_xor(s, 16, 64);
  s += __shfl_xor(s, 32, 64);
  float invdeg = 1.f / fmaxf((float)(endReal - beg), 1.f);
  s *= invdeg;
  float nxt = __shfl_down(s, 1, 64);
  if (lane < 8 && !(lane & 1)) {
    h2 v; v.x = (_Float16)s; v.y = (_Float16)nxt;
    lattrh[(size_t)d * 4 + (lane >> 1)] = v;
  }
}

// ---------------- lin1: bf16 xl1 + f32 xrb1 (permpos, biases folded) ----------------
__global__ __launch_bounds__(256) void k_lin1(const float* __restrict__ x,
                                              const float* __restrict__ wl, const float* __restrict__ bl,
                                              const float* __restrict__ wr, const float* __restrict__ br,
                                              unsigned short* __restrict__ xl, float* __restrict__ xr) {
  __shared__ float xs[4][16];
  int nb = blockIdx.x * 4;
  int t = threadIdx.x;
  if (t < 64) xs[t >> 4][t & 15] = x[nb * 16 + t];
  __syncthreads();
  int w = t >> 6, lane = t & 63, l4 = lane << 2;
  float4 accl = *(const float4*)(bl + l4);
  float4 accr = *(const float4*)(br + l4);
  const float* xrow = xs[w];
#pragma unroll
  for (int k = 0; k < 16; k++) {
    float xv = xrow[k];
    float4 wl4 = *(const float4*)(wl + k * 256 + l4);
    float4 wr4 = *(const float4*)(wr + k * 256 + l4);
    accl.x += xv * wl4.x; accl.y += xv * wl4.y; accl.z += xv * wl4.z; accl.w += xv * wl4.w;
    accr.x += xv * wr4.x; accr.y += xv * wr4.y; accr.z += xv * wr4.z; accr.w += xv * wr4.w;
  }
  int node = nb + w;
  ushort4 us;
  us.x = f2bf(accl.x); us.y = f2bf(accl.y); us.z = f2bf(accl.z); us.w = f2bf(accl.w);
  *(ushort4*)(xl + (size_t)node * 256 + l4) = us;
  *(float4*)(xr + (size_t)node * 256 + l4) = accr;
}

// scalar edge-attr pointer (eid wave-uniform), half2 domain
__device__ __forceinline__ const h2* ekh_ptr(const h2* __restrict__ ehalf,
                                             const h2* __restrict__ lattrh, int eid) {
  return (eid < NE) ? (ehalf + (size_t)eid * 4) : (lattrh + (size_t)(eid - NE) * 4);
}

// j-space logit reduction (conv1): 7 shuffles.
__device__ __forceinline__ float jreduce(float part[4]) {
  part[0] += __shfl_xor(part[1], 1, 64);
  part[2] += __shfl_xor(part[3], 1, 64);
  float v = part[0] + __shfl_xor(part[2], 2, 64);
  v += __shfl_xor(v, 4, 64);
  v += __shfl_xor(v, 8, 64);
  v += __shfl_xor(v, 16, 64);
  v += __shfl_xor(v, 32, 64);
  return v;
}

// ---------------- conv1: GATv2 4 heads, 4-edge groups, fdot2 MLP, exp2 softmax ----------------
__global__ __launch_bounds__(256) void k_conv1(
    const h2* __restrict__ ehalf, const h2* __restrict__ lattrh,
    const int* __restrict__ rowptr, const int2* __restrict__ csr,
    const unsigned short* __restrict__ xl, const float* __restrict__ xrg,
    const float* __restrict__ att1p, const float* __restrict__ bias1p,
    const h2* __restrict__ wfh1,
    float* __restrict__ out1) {
  int d = __builtin_amdgcn_readfirstlane((blockIdx.x * blockDim.x + threadIdx.x) >> 6);
  int lane = threadIdx.x & 63;
  if (d >= NN) return;
  int l4 = lane << 2;
  float4 xr4 = *(const float4*)(xrg + (size_t)d * 256 + l4);
  float4 at4 = *(const float4*)(att1p + l4);
  h2 wf[4][4];
#pragma unroll
  for (int k2 = 0; k2 < 4; k2++) {
#pragma unroll
    for (int slot = 0; slot < 4; slot++) wf[slot][k2] = wfh1[k2 * 256 + l4 + slot];
  }

  float acc0 = 0.f, acc1 = 0.f, acc2 = 0.f, acc3 = 0.f;
  float mrun = -INFINITY, lrun = 0.f;
  int beg = rowptr[d], end = rowptr[d + 1];

  auto ld4 = [&](int s) -> float4 {
    ushort4 u = *(const ushort4*)(xl + (size_t)s * 256 + l4);
    float4 f; f.x = bf2f(u.x); f.y = bf2f(u.y); f.z = bf2f(u.z); f.w = bf2f(u.w);
    return f;
  };
  auto epart = [&](const h2* __restrict__ p, const float4& x4, float part[4]) {
    h2 a0 = p[0], a1 = p[1], a2 = p[2], a3 = p[3];
    float e0 = 0.f, e1 = 0.f, e2 = 0.f, e3 = 0.f;
    e0 = FDOT2(wf[0][0], a0, e0); e0 = FDOT2(wf[0][1], a1, e0);
    e0 = FDOT2(wf[0][2], a2, e0); e0 = FDOT2(wf[0][3], a3, e0);
    e1 = FDOT2(wf[1][0], a0, e1); e1 = FDOT2(wf[1][1], a1, e1);
    e1 = FDOT2(wf[1][2], a2, e1); e1 = FDOT2(wf[1][3], a3, e1);
    e2 = FDOT2(wf[2][0], a0, e2); e2 = FDOT2(wf[2][1], a1, e2);
    e2 = FDOT2(wf[2][2], a2, e2); e2 = FDOT2(wf[2][3], a3, e2);
    e3 = FDOT2(wf[3][0], a0, e3); e3 = FDOT2(wf[3][1], a1, e3);
    e3 = FDOT2(wf[3][2], a2, e3); e3 = FDOT2(wf[3][3], a3, e3);
    float m0 = x4.x + xr4.x + e0; m0 = (m0 > 0.f) ? m0 : 0.2f * m0;
    float m1 = x4.y + xr4.y + e1; m1 = (m1 > 0.f) ? m1 : 0.2f * m1;
    float m2 = x4.z + xr4.z + e2; m2 = (m2 > 0.f) ? m2 : 0.2f * m2;
    float m3 = x4.w + xr4.w + e3; m3 = (m3 > 0.f) ? m3 : 0.2f * m3;
    part[0] = at4.x * m0; part[1] = at4.y * m1;
    part[2] = at4.z * m2; part[3] = at4.w * m3;
  };

  int idx = beg;
  for (; idx + 4 <= end; idx += 4) {
    int2 e0 = csr[idx], e1 = csr[idx + 1], e2 = csr[idx + 2], e3 = csr[idx + 3];
    int s0 = __builtin_amdgcn_readfirstlane(e0.y), id0 = __builtin_amdgcn_readfirstlane(e0.x);
    int s1 = __builtin_amdgcn_readfirstlane(e1.y), id1 = __builtin_amdgcn_readfirstlane(e1.x);
    int s2 = __builtin_amdgcn_readfirstlane(e2.y), id2 = __builtin_amdgcn_readfirstlane(e2.x);
    int s3 = __builtin_amdgcn_readfirstlane(e3.y), id3 = __builtin_amdgcn_readfirstlane(e3.x);
    float4 x0 = ld4(s0), x1 = ld4(s1), x2 = ld4(s2), x3 = ld4(s3);
    float pa[4], pb[4], pc[4], pd[4];
    epart(ekh_ptr(ehalf, lattrh, id0), x0, pa);
    epart(ekh_ptr(ehalf, lattrh, id1), x1, pb);
    epart(ekh_ptr(ehalf, lattrh, id2), x2, pc);
    epart(ekh_ptr(ehalf, lattrh, id3), x3, pd);
    float v0 = jreduce(pa), v1 = jreduce(pb), v2 = jreduce(pc), v3 = jreduce(pd);
    float gmax = fmaxf(fmaxf(v0, v1), fmaxf(v2, v3));
    if (__ballot(gmax > mrun)) {
      float nm = fmaxf(mrun, gmax);
      float sc = exp2f(mrun - nm);
      mrun = nm; lrun *= sc;
      float sc1 = __shfl_xor(sc, 1, 64);
      float sc2 = __shfl_xor(sc, 2, 64);
      float sc3 = __shfl_xor(sc1, 2, 64);
      acc0 *= sc; acc1 *= sc1; acc2 *= sc2; acc3 *= sc3;
    }
    float q0 = exp2f(v0 - mrun), q1 = exp2f(v1 - mrun);
    float q2 = exp2f(v2 - mrun), q3 = exp2f(v3 - mrun);
    lrun += (q0 + q1) + (q2 + q3);
    {
      float a1 = __shfl_xor(q0, 1, 64), a2 = __shfl_xor(q0, 2, 64), a3 = __shfl_xor(a1, 2, 64);
      acc0 += q0 * x0.x; acc1 += a1 * x0.y; acc2 += a2 * x0.z; acc3 += a3 * x0.w;
    }
    {
      float a1 = __shfl_xor(q1, 1, 64), a2 = __shfl_xor(q1, 2, 64), a3 = __shfl_xor(a1, 2, 64);
      acc0 += q1 * x1.x; acc1 += a1 * x1.y; acc2 += a2 * x1.z; acc3 += a3 * x1.w;
    }
    {
      float a1 = __shfl_xor(q2, 1, 64), a2 = __shfl_xor(q2, 2, 64), a3 = __shfl_xor(a1, 2, 64);
      acc0 += q2 * x2.x; acc1 += a1 * x2.y; acc2 += a2 * x2.z; acc3 += a3 * x2.w;
    }
    {
      float a1 = __shfl_xor(q3, 1, 64), a2 = __shfl_xor(q3, 2, 64), a3 = __shfl_xor(a1, 2, 64);
      acc0 += q3 * x3.x; acc1 += a1 * x3.y; acc2 += a2 * x3.z; acc3 += a3 * x3.w;
    }
  }
  for (; idx < end; ++idx) {
    int2 e0 = csr[idx];
    int s0 = __builtin_amdgcn_readfirstlane(e0.y), id0 = __builtin_amdgcn_readfirstlane(e0.x);
    float4 x0 = ld4(s0);
    float pa[4];
    epart(ekh_ptr(ehalf, lattrh, id0), x0, pa);
    float v0 = jreduce(pa);
    if (__ballot(v0 > mrun)) {
      float nm = fmaxf(mrun, v0);
      float sc = exp2f(mrun - nm);
      mrun = nm; lrun *= sc;
      float sc1 = __shfl_xor(sc, 1, 64);
      float sc2 = __shfl_xor(sc, 2, 64);
      float sc3 = __shfl_xor(sc1, 2, 64);
      acc0 *= sc; acc1 *= sc1; acc2 *= sc2; acc3 *= sc3;
    }
    float q0 = exp2f(v0 - mrun);
    lrun += q0;
    float a1 = __shfl_xor(q0, 1, 64), a2 = __shfl_xor(q0, 2, 64), a3 = __shfl_xor(a1, 2, 64);
    acc0 += q0 * x0.x; acc1 += a1 * x0.y; acc2 += a2 * x0.z; acc3 += a3 * x0.w;
  }

  float lr0 = lrun;
  float lr1 = __shfl_xor(lr0, 1, 64);
  float lr2 = __shfl_xor(lr0, 2, 64);
  float lr3 = __shfl_xor(lr1, 2, 64);
  float4 bi4 = *(const float4*)(bias1p + l4);
  float4 o;
  o.x = acc0 / (lr0 + 1e-16f) + bi4.x;
  o.y = acc1 / (lr1 + 1e-16f) + bi4.y;
  o.z = acc2 / (lr2 + 1e-16f) + bi4.z;
  o.w = acc3 / (lr3 + 1e-16f) + bi4.w;
  o.x = (o.x > 0.f) ? o.x : (__expf(o.x) - 1.f);
  o.y = (o.y > 0.f) ? o.y : (__expf(o.y) - 1.f);
  o.z = (o.z > 0.f) ? o.z : (__expf(o.z) - 1.f);
  o.w = (o.w > 0.f) ? o.w : (__expf(o.w) - 1.f);
  *(float4*)(out1 + (size_t)d * 256 + l4) = o;
}

// ---------------- lin2: permpos out1 -> bf16 xl2 + f32 xrb2 (bfe2 folded) ----------------
__global__ __launch_bounds__(256) void k_lin2(const float* __restrict__ in,
                                              const float* __restrict__ wl, const float* __restrict__ bl,
                                              const float* __restrict__ wr, const float* __restrict__ br,
                                              const float* __restrict__ bfe2,
                                              unsigned short* __restrict__ xl, float* __restrict__ xr) {
  int col = threadIdx.x & 63;
  int grp = threadIdx.x >> 6;
  int node0 = blockIdx.x * 32 + grp * 8;
  float sl[8], sr[8];
  float blv = bl[col], brv = br[col] + bfe2[col];
#pragma unroll
  for (int u = 0; u < 8; u++) { sl[u] = blv; sr[u] = brv; }
  const float4* r[8];
#pragma unroll
  for (int u = 0; u < 8; u++) r[u] = (const float4*)(in + (size_t)(node0 + u) * 256);
#pragma unroll 2
  for (int g4 = 0; g4 < 64; g4++) {
    int b = g4 & 3;
    int i0 = ((0 ^ b) << 6) + g4;
    int i1 = ((1 ^ b) << 6) + g4;
    int i2 = ((2 ^ b) << 6) + g4;
    int i3 = ((3 ^ b) << 6) + g4;
    float wl0 = wl[i0 * 64 + col], wl1v = wl[i1 * 64 + col];
    float wl2v = wl[i2 * 64 + col], wl3v = wl[i3 * 64 + col];
    float wr0 = wr[i0 * 64 + col], wr1v = wr[i1 * 64 + col];
    float wr2v = wr[i2 * 64 + col], wr3v = wr[i3 * 64 + col];
#pragma unroll
    for (int u = 0; u < 8; u++) {
      float4 v = r[u][g4];
      sl[u] += v.x * wl0 + v.y * wl1v + v.z * wl2v + v.w * wl3v;
      sr[u] += v.x * wr0 + v.y * wr1v + v.z * wr2v + v.w * wr3v;
    }
  }
#pragma unroll
  for (int u = 0; u < 8; u++) {
    int node = node0 + u;
    if (node < NN) {
      xl[(size_t)node * 64 + col] = f2bf(sl[u]);
      xr[(size_t)node * 64 + col] = sr[u];
    }
  }
}

// ---------------- conv2: 1 head, pair-merge reduce, fdot2 MLP, exp2 softmax ----------------
__global__ __launch_bounds__(256) void k_conv2(
    const h2* __restrict__ ehalf, const h2* __restrict__ lattrh,
    const int* __restrict__ rowptr, const int2* __restrict__ csr,
    const unsigned short* __restrict__ xl, const float* __restrict__ xrg,
    const float* __restrict__ att2p, const float* __restrict__ bias2,
    const h2* __restrict__ wfh2,
    float* __restrict__ out2) {
  int d = __builtin_amdgcn_readfirstlane((blockIdx.x * blockDim.x + threadIdx.x) >> 6);
  int lane = threadIdx.x & 63;
  if (d >= NN) return;
  float xr_l = xrg[(size_t)d * 64 + lane];
  float att_l = att2p[lane];
  h2 wfh_l[4];
#pragma unroll
  for (int k2 = 0; k2 < 4; k2++) wfh_l[k2] = wfh2[k2 * 64 + lane];
  float acc = 0.f, mrun = -INFINITY, lrun = 0.f;
  int beg = rowptr[d], end = rowptr[d + 1];
  bool b0 = (lane & 1), b1 = (lane & 2);

  auto pl = [&](const h2* __restrict__ p, float xs) {
    h2 a0 = p[0], a1 = p[1], a2 = p[2], a3 = p[3];
    float ep = 0.f;
    ep = FDOT2(wfh_l[0], a0, ep); ep = FDOT2(wfh_l[1], a1, ep);
    ep = FDOT2(wfh_l[2], a2, ep); ep = FDOT2(wfh_l[3], a3, ep);
    float m = xs + xr_l + ep;
    m = (m > 0.f) ? m : 0.2f * m;
    return att_l * m;  // per-lane partial (log2 domain)
  };

  int idx = beg;
  for (; idx + 4 <= end; idx += 4) {
    int2 e0 = csr[idx], e1 = csr[idx + 1], e2 = csr[idx + 2], e3 = csr[idx + 3];
    int s0 = __builtin_amdgcn_readfirstlane(e0.y), id0 = __builtin_amdgcn_readfirstlane(e0.x);
    int s1 = __builtin_amdgcn_readfirstlane(e1.y), id1 = __builtin_amdgcn_readfirstlane(e1.x);
    int s2 = __builtin_amdgcn_readfirstlane(e2.y), id2 = __builtin_amdgcn_readfirstlane(e2.x);
    int s3 = __builtin_amdgcn_readfirstlane(e3.y), id3 = __builtin_amdgcn_readfirstlane(e3.x);
    float x0 = bf2f(xl[(size_t)s0 * 64 + lane]);
    float x1 = bf2f(xl[(size_t)s1 * 64 + lane]);
    float x2 = bf2f(xl[(size_t)s2 * 64 + lane]);
    float x3 = bf2f(xl[(size_t)s3 * 64 + lane]);
    float v0 = pl(ekh_ptr(ehalf, lattrh, id0), x0);
    float v1 = pl(ekh_ptr(ehalf, lattrh, id1), x1);
    float v2 = pl(ekh_ptr(ehalf, lattrh, id2), x2);
    float v3 = pl(ekh_ptr(ehalf, lattrh, id3), x3);
    // pair-merge butterfly: lane ends owning edge (lane&3)'s full logit
    float a01 = b0 ? v1 : v0;
    a01 += __shfl_xor(b0 ? v0 : v1, 1, 64);
    float a23 = b0 ? v3 : v2;
    a23 += __shfl_xor(b0 ? v2 : v3, 1, 64);
    float w = b1 ? a23 : a01;
    w += __shfl_xor(b1 ? a01 : a23, 2, 64);
    w += __shfl_xor(w, 4, 64);
    w += __shfl_xor(w, 8, 64);
    w += __shfl_xor(w, 16, 64);
    w += __shfl_xor(w, 32, 64);  // full logit of edge lane&3
    float g = fmaxf(w, __shfl_xor(w, 1, 64));
    g = fmaxf(g, __shfl_xor(g, 2, 64));  // uniform group max
    if (g > mrun) {
      float sc = exp2f(mrun - g);
      mrun = g; lrun *= sc; acc *= sc;
    }
    float q = exp2f(w - mrun);           // 1 exp: edge lane&3
    float q1 = __shfl_xor(q, 1, 64);
    float q2 = __shfl_xor(q, 2, 64);
    float q3 = __shfl_xor(q1, 2, 64);
    lrun += (q + q1) + (q2 + q3);        // uniform
    float u01 = b0 ? x1 : x0, u10 = b0 ? x0 : x1;
    float u23 = b0 ? x3 : x2, u32 = b0 ? x2 : x3;
    float xr0 = b1 ? u23 : u01;
    float xr1v = b1 ? u32 : u10;
    float xr2v = b1 ? u01 : u23;
    float xr3v = b1 ? u10 : u32;
    acc += q * xr0 + q1 * xr1v + q2 * xr2v + q3 * xr3v;
  }
  for (; idx < end; ++idx) {
    int2 e0 = csr[idx];
    int s0 = __builtin_amdgcn_readfirstlane(e0.y), id0 = __builtin_amdgcn_readfirstlane(e0.x);
    float x0 = bf2f(xl[(size_t)s0 * 64 + lane]);
    float v = pl(ekh_ptr(ehalf, lattrh, id0), x0);
    v += __shfl_xor(v, 1, 64);
    v += __shfl_xor(v, 2, 64);
    v += __shfl_xor(v, 4, 64);
    v += __shfl_xor(v, 8, 64);
    v += __shfl_xor(v, 16, 64);
    v += __shfl_xor(v, 32, 64);
    if (v > mrun) {
      float sc = exp2f(mrun - v);
      mrun = v; lrun *= sc; acc *= sc;
    }
    float q = exp2f(v - mrun);
    lrun += q;
    acc += q * x0;
  }
  out2[(size_t)d * 64 + lane] = acc / (lrun + 1e-16f) + bias2[lane];
}

// ---------------- global mean pool ----------------
__device__ __forceinline__ int lowerb(const int* a, int n, int v) {
  int lo = 0, hi = n;
  while (lo < hi) {
    int mid = (lo + hi) >> 1;
    if (a[mid] < v) lo = mid + 1; else hi = mid;
  }
  return lo;
}

__global__ __launch_bounds__(256) void k_pool(const int* __restrict__ batch,
                                              const float* __restrict__ out2,
                                              float* __restrict__ pooled) {
  int b = blockIdx.x;
  int start = lowerb(batch, NN, b);
  int end = lowerb(batch, NN, b + 1);
  int c = threadIdx.x & 63, sub = threadIdx.x >> 6;
  float s = 0.f;
  for (int i = start + sub; i < end; i += 4) s += out2[(size_t)i * 64 + c];
  __shared__ float sm[256];
  sm[threadIdx.x] = s;
  __syncthreads();
  if (sub == 0) {
    float tot = sm[c] + sm[64 + c] + sm[128 + c] + sm[192 + c];
    float cnt = fmaxf((float)(end - start), 1.f);
    pooled[b * 64 + c] = tot / cnt;
  }
}

// ---------------- decoder ----------------
__global__ __launch_bounds__(1024) void k_dec(const float* __restrict__ pooled,
                                              const float* __restrict__ Wd1, const float* __restrict__ bd1,
                                              const float* __restrict__ Wd2, const float* __restrict__ bd2,
                                              float* __restrict__ out) {
  __shared__ float hid[64 * 64];
  int t = threadIdx.x;
  for (int i = t; i < 4096; i += 1024) {
    int b = i >> 6, j = i & 63;
    float s = bd1[j];
#pragma unroll 8
    for (int k = 0; k < 64; k++) s += pooled[b * 64 + k] * Wd1[k * 64 + j];
    hid[i] = fmaxf(s, 0.f);
  }
  __syncthreads();
  if (t < 128) {
    int b = t >> 1, o = t & 1;
    float s = bd2[o];
#pragma unroll 8
    for (int k = 0; k < 64; k++) s += hid[b * 64 + k] * Wd2[k * 2 + o];
    out[t] = 1.f / (1.f + __expf(-s));
  }
}

extern "C" void kernel_launch(void* const* d_in, const int* in_sizes, int n_in,
                              void* d_out, int out_size, void* d_ws, size_t ws_size,
                              hipStream_t stream) {
  const float* x     = (const float*)d_in[0];
  const int*   eidx  = (const int*)d_in[1];
  const float* eattr = (const float*)d_in[2];
  const int*   batch = (const int*)d_in[3];
  const float* Wn    = (const float*)d_in[4];
  const float* bn    = (const float*)d_in[5];
  const float* We    = (const float*)d_in[6];
  const float* be    = (const float*)d_in[7];
  const float* Wl1   = (const float*)d_in[8];
  const float* bl1   = (const float*)d_in[9];
  const float* Wr1   = (const float*)d_in[10];
  const float* br1   = (const float*)d_in[11];
  const float* We1   = (const float*)d_in[12];
  const float* att1  = (const float*)d_in[13];
  const float* bias1 = (const float*)d_in[14];
  const float* Wl2   = (const float*)d_in[15];
  const float* bl2   = (const float*)d_in[16];
  const float* Wr2   = (const float*)d_in[17];
  const float* br2   = (const float*)d_in[18];
  const float* We2   = (const float*)d_in[19];
  const float* att2  = (const float*)d_in[20];
  const float* bias2 = (const float*)d_in[21];
  const float* Wd1   = (const float*)d_in[22];
  const float* bd1   = (const float*)d_in[23];
  const float* Wd2   = (const float*)d_in[24];
  const float* bd2   = (const float*)d_in[25];

  const int* srcA = eidx;
  const int* dstA = eidx + NE;

  char* ws = (char*)d_ws;
  size_t off = 0;
  auto alloc = [&](size_t bytes) -> char* {
    char* p = ws + off;
    off += (bytes + 255) & ~(size_t)255;
    return p;
  };

  // zero region (deg, cursor) must stay first & contiguous
  int*   deg    = (int*)alloc(NN * 4);
  int*   cursor = (int*)alloc(NN * 4);
  size_t zero_bytes = off;
  int*   rowptr   = (int*)alloc((NN + 1) * 4);
  int*   incl     = (int*)alloc(NN * 4);
  int*   partials = (int*)alloc(64 * 4);
  int2*  csr      = (int2*)alloc((size_t)(NE + NN + 1) * 8);
  h2*    ehalf  = (h2*)alloc((size_t)NE * 4 * 4);
  h2*    lattrh = (h2*)alloc((size_t)NN * 4 * 4);
  float* wl1e  = (float*)alloc(4096 * 4);
  float* wr1e  = (float*)alloc(4096 * 4);
  h2*    wfh1  = (h2*)alloc(1024 * 4);
  h2*    wfh2  = (h2*)alloc(256 * 4);
  float* bl1e  = (float*)alloc(256 * 4);
  float* br1e  = (float*)alloc(256 * 4);
  float* bfe2  = (float*)alloc(64 * 4);
  float* att1p = (float*)alloc(256 * 4);
  float* att2p = (float*)alloc(64 * 4);
  float* bias1p= (float*)alloc(256 * 4);
  unsigned short* xl1 = (unsigned short*)alloc((size_t)NN * 256 * 2);
  float* xrb1  = (float*)alloc((size_t)NN * 256 * 4);
  float* out1  = (float*)alloc((size_t)NN * 256 * 4);
  unsigned short* xl2 = (unsigned short*)alloc((size_t)NN * 64 * 2);
  float* xrb2  = (float*)alloc((size_t)NN * 64 * 4);
  float* out2  = (float*)alloc((size_t)NN * 64 * 4);
  float* pooled = (float*)alloc((size_t)NB * 64 * 4);

  int zn = (int)(zero_bytes / 4);
  int nscan = (NN + 1023) / 1024;  // 49
  k_zero<<<(zn + 255) / 256, 256, 0, stream>>>((int*)d_ws, zn);
  k_fuse<<<(10624 + 255) / 256, 256, 0, stream>>>(Wn, bn, We, be, Wl1, bl1, Wr1, br1, We1, We2,
                                                  att1, bias1, att2,
                                                  wl1e, bl1e, wr1e, br1e, wfh1, wfh2, bfe2,
                                                  att1p, att2p, bias1p);
  k_toh<<<(NE + 255) / 256, 256, 0, stream>>>(eattr, ehalf);
  k_deg<<<(NE + 255) / 256, 256, 0, stream>>>(dstA, deg);
  k_scan1<<<nscan, 1024, 0, stream>>>(deg, incl, partials);
  k_scan2<<<1, 64, 0, stream>>>(partials, rowptr, nscan);
  k_scan3<<<(NN + 255) / 256, 256, 0, stream>>>(deg, incl, partials, rowptr);
  k_csr<<<(NE + NN + 255) / 256, 256, 0, stream>>>(srcA, dstA, rowptr, deg, cursor, csr);
  k_loop8<<<(NN + 3) / 4, 256, 0, stream>>>(rowptr, csr, eattr, lattrh);
  k_lin1<<<NN / 4, 256, 0, stream>>>(x, wl1e, bl1e, wr1e, br1e, xl1, xrb1);
  k_conv1<<<(NN + 3) / 4, 256, 0, stream>>>(ehalf, lattrh, rowptr, csr, xl1, xrb1,
                                            att1p, bias1p, wfh1, out1);
  k_lin2<<<(NN + 31) / 32, 256, 0, stream>>>(out1, Wl2, bl2, Wr2, br2, bfe2, xl2, xrb2);
  k_conv2<<<(NN + 3) / 4, 256, 0, stream>>>(ehalf, lattrh, rowptr, csr, xl2, xrb2,
                                            att2p, bias2, wfh2, out2);
  k_pool<<<NB, 256, 0, stream>>>(batch, out2, pooled);
  k_dec<<<1, 1024, 0, stream>>>(pooled, Wd1, bd1, Wd2, bd2, (float*)d_out);
}